// Round 1
// baseline (919.598 us; speedup 1.0000x reference)
//
#include <hip/hip_runtime.h>
#include <hip/hip_bf16.h>
#include <math.h>

// ---------------- CSR build ----------------
__global__ void k_init(int* deg, float* gsum, float* gcnt, int n, int G) {
  int i = blockIdx.x * blockDim.x + threadIdx.x;
  if (i < n) deg[i] = 1;             // self loop contributes 1 to every node
  if (i < G * 8) gsum[i] = 0.f;
  if (i < G) gcnt[i] = 0.f;
}

__global__ void k_hist(const int* __restrict__ ei, int* deg, int E) {
  int i = blockIdx.x * blockDim.x + threadIdx.x;
  if (i < E) atomicAdd(&deg[ei[E + i]], 1);   // dst row of edge_index
}

__global__ void k_reduce(const int* __restrict__ deg, int* bsum, int n) {
  int i = blockIdx.x * 256 + threadIdx.x;
  int v = (i < n) ? deg[i] : 0;
  #pragma unroll
  for (int off = 32; off; off >>= 1) v += __shfl_down(v, off, 64);
  __shared__ int sh[4];
  if ((threadIdx.x & 63) == 0) sh[threadIdx.x >> 6] = v;
  __syncthreads();
  if (threadIdx.x == 0) bsum[blockIdx.x] = sh[0] + sh[1] + sh[2] + sh[3];
}

// single-block inclusive->exclusive scan of block sums (nb <= 512)
__global__ void k_scan_bsum(int* bsum, int nb) {
  __shared__ int sh[512];
  int t = threadIdx.x;
  int v = (t < nb) ? bsum[t] : 0;
  sh[t] = v; __syncthreads();
  for (int off = 1; off < 512; off <<= 1) {
    int add = (t >= off) ? sh[t - off] : 0;
    __syncthreads();
    sh[t] += add;
    __syncthreads();
  }
  if (t < nb) bsum[t] = sh[t] - v;   // exclusive
}

__global__ void k_scan_final(const int* __restrict__ deg, const int* __restrict__ bsum,
                             int* csr_ptr, int* cursor, int n) {
  __shared__ int sh[256];
  int t = threadIdx.x; int i = blockIdx.x * 256 + t;
  int v = (i < n) ? deg[i] : 0;
  sh[t] = v; __syncthreads();
  for (int off = 1; off < 256; off <<= 1) {
    int add = (t >= off) ? sh[t - off] : 0;
    __syncthreads();
    sh[t] += add;
    __syncthreads();
  }
  int excl = sh[t] - v + bsum[blockIdx.x];
  if (i < n) { csr_ptr[i] = excl; cursor[i] = excl; }
  if (i == n - 1) csr_ptr[n] = excl + v;
}

__global__ void k_scatter(const int* __restrict__ ei, int* cursor, int* csr_src,
                          int E, int n) {
  int i = blockIdx.x * blockDim.x + threadIdx.x;
  if (i >= E + n) return;
  int s, d;
  if (i < E) { s = ei[i]; d = ei[E + i]; } else { s = d = i - E; }
  int pos = atomicAdd(&cursor[d], 1);
  csr_src[pos] = s;
}

// ---------------- layer 1 transform: xl1 = x@W1l, xr1 = x@W1r ----------------
__global__ __launch_bounds__(256) void k_gemm1(const float* __restrict__ x,
    const float* __restrict__ Wl, const float* __restrict__ Wr,
    float* __restrict__ xl, float* __restrict__ xr, int n) {
  __shared__ float xs[64 * 132];     // 64 rows x 128, padded to 132 (bank spread)
  __shared__ float Ws[128 * 32];     // [k][c] c<16: Wl, c>=16: Wr
  int t = threadIdx.x;
  int r0 = blockIdx.x * 64;
  #pragma unroll
  for (int i = 0; i < 8; i++) {
    int idx = t + i * 256;           // 0..2047
    int k = idx >> 4, c = idx & 15;
    Ws[k * 32 + c]      = Wl[idx];
    Ws[k * 32 + 16 + c] = Wr[idx];
  }
  #pragma unroll
  for (int i = 0; i < 8; i++) {
    int v = t + i * 256;             // float4 units, 32 per row
    int row = v >> 5;
    int col4 = v & 31;
    float4 val = make_float4(0.f, 0.f, 0.f, 0.f);
    if (r0 + row < n)
      val = reinterpret_cast<const float4*>(x)[(long)(r0 + row) * 32 + col4];
    float* dst = &xs[row * 132 + col4 * 4];
    dst[0] = val.x; dst[1] = val.y; dst[2] = val.z; dst[3] = val.w;
  }
  __syncthreads();
  int g = t >> 2;                    // row in tile 0..63
  int sub = t & 3;                   // 8-col group
  float acc[8] = {0.f,0.f,0.f,0.f,0.f,0.f,0.f,0.f};
  #pragma unroll 4
  for (int k = 0; k < 128; k++) {
    float xv = xs[g * 132 + k];
    const float4* wp = reinterpret_cast<const float4*>(&Ws[k * 32 + sub * 8]);
    float4 w0 = wp[0], w1 = wp[1];
    acc[0] += xv * w0.x; acc[1] += xv * w0.y; acc[2] += xv * w0.z; acc[3] += xv * w0.w;
    acc[4] += xv * w1.x; acc[5] += xv * w1.y; acc[6] += xv * w1.z; acc[7] += xv * w1.w;
  }
  int row = r0 + g;
  if (row < n) {
    float* o = (sub < 2) ? &xl[(long)row * 16 + sub * 8]
                         : &xr[(long)row * 16 + (sub - 2) * 8];
    float4* o4 = reinterpret_cast<float4*>(o);
    o4[0] = make_float4(acc[0], acc[1], acc[2], acc[3]);
    o4[1] = make_float4(acc[4], acc[5], acc[6], acc[7]);
  }
}

// ---------------- layer 2 transform: xl2 = h@W2l, xr2 = h@W2r ----------------
__global__ void k_gemm2(const float* __restrict__ h,
    const float* __restrict__ Wl, const float* __restrict__ Wr,
    float* __restrict__ xl, float* __restrict__ xr, int n) {
  __shared__ float Wls[128], Wrs[128];
  int t = threadIdx.x;
  if (t < 128) { Wls[t] = Wl[t]; Wrs[t] = Wr[t]; }
  __syncthreads();
  int i = blockIdx.x * blockDim.x + t;
  if (i >= n) return;
  float hv[16];
  const float4* hp = reinterpret_cast<const float4*>(h + (long)i * 16);
  #pragma unroll
  for (int q = 0; q < 4; q++) {
    float4 v = hp[q];
    hv[q*4] = v.x; hv[q*4+1] = v.y; hv[q*4+2] = v.z; hv[q*4+3] = v.w;
  }
  float al[8] = {0,0,0,0,0,0,0,0}, ar[8] = {0,0,0,0,0,0,0,0};
  #pragma unroll
  for (int k = 0; k < 16; k++) {
    #pragma unroll
    for (int c = 0; c < 8; c++) {
      al[c] += hv[k] * Wls[k * 8 + c];
      ar[c] += hv[k] * Wrs[k * 8 + c];
    }
  }
  float4* xlp = reinterpret_cast<float4*>(xl + (long)i * 8);
  float4* xrp = reinterpret_cast<float4*>(xr + (long)i * 8);
  xlp[0] = make_float4(al[0], al[1], al[2], al[3]);
  xlp[1] = make_float4(al[4], al[5], al[6], al[7]);
  xrp[0] = make_float4(ar[0], ar[1], ar[2], ar[3]);
  xrp[1] = make_float4(ar[4], ar[5], ar[6], ar[7]);
}

// ------------- pull-style GATv2 aggregation, online softmax, C lanes/node -------------
template<int C>
__global__ __launch_bounds__(256) void k_edge(const int* __restrict__ csr_ptr,
    const int* __restrict__ csr_src, const float* __restrict__ xl,
    const float* __restrict__ xr, const float* __restrict__ att,
    const float* __restrict__ bias, float* __restrict__ out, int n) {
  int t = threadIdx.x;
  const int gpb = 256 / C;
  int node = blockIdx.x * gpb + t / C;
  int c = t % C;
  if (node >= n) return;
  int beg = csr_ptr[node], end = csr_ptr[node + 1];
  float xr_c = xr[(long)node * C + c];
  float a_c = att[c];
  float m = -INFINITY, s = 0.f, num = 0.f;
  for (int i = beg; i < end; ++i) {
    int src = csr_src[i];
    float xl_c = xl[(long)src * C + c];
    float v = xl_c + xr_c;
    v = (v > 0.f) ? v : 0.2f * v;          // leaky_relu 0.2
    float p = v * a_c;
    #pragma unroll
    for (int off = C / 2; off > 0; off >>= 1) p += __shfl_xor(p, off, 64);
    float e = p;                            // all C lanes hold edge score
    float mn = fmaxf(m, e);
    float sc = __expf(m - mn);              // first iter: exp(-inf)=0
    float pe = __expf(e - mn);
    s = s * sc + pe;
    num = num * sc + pe * xl_c;
    m = mn;
  }
  float o = num / fmaxf(s, 1e-16f) + bias[c];
  out[(long)node * C + c] = fmaxf(o, 0.f);  // relu (both layers use relu)
}

// ---------------- mean pool + linear ----------------
__global__ void k_pool(const float* __restrict__ h, const int* __restrict__ batch,
                       float* gsum, float* gcnt, int n) {
  int i = blockIdx.x * blockDim.x + threadIdx.x;
  if (i >= n) return;
  int g = batch[i];
  #pragma unroll
  for (int c = 0; c < 8; c++) atomicAdd(&gsum[g * 8 + c], h[(long)i * 8 + c]);
  atomicAdd(&gcnt[g], 1.f);
}

__global__ void k_final(const float* __restrict__ gsum, const float* __restrict__ gcnt,
                        const float* __restrict__ Wlin, const float* __restrict__ blin,
                        float* out, int G) {
  int g = blockIdx.x * blockDim.x + threadIdx.x;
  if (g >= G) return;
  float cnt = fmaxf(gcnt[g], 1.f);
  float acc = 0.f;
  #pragma unroll
  for (int c = 0; c < 8; c++) acc += (gsum[g * 8 + c] / cnt) * Wlin[c];
  out[g] = acc + blin[0];
}

extern "C" void kernel_launch(void* const* d_in, const int* in_sizes, int n_in,
                              void* d_out, int out_size, void* d_ws, size_t ws_size,
                              hipStream_t stream) {
  (void)n_in; (void)ws_size;
  const float* x    = (const float*)d_in[0];
  const int*   ei   = (const int*)d_in[1];
  const int*   batch= (const int*)d_in[2];
  const float* W1l  = (const float*)d_in[3];
  const float* W1r  = (const float*)d_in[4];
  const float* a1   = (const float*)d_in[5];
  const float* b1   = (const float*)d_in[6];
  const float* W2l  = (const float*)d_in[7];
  const float* W2r  = (const float*)d_in[8];
  const float* a2   = (const float*)d_in[9];
  const float* b2   = (const float*)d_in[10];
  const float* Wlin = (const float*)d_in[11];
  const float* blin = (const float*)d_in[12];
  float* out = (float*)d_out;

  int N = in_sizes[0] / 128;
  int E = in_sizes[1] / 2;
  int G = out_size;            // 256 graphs, output [G,1]
  int ET = E + N;              // edges incl self loops

  char* ws = (char*)d_ws;
  size_t off = 0;
  auto alloc = [&](size_t bytes) {
    void* p = ws + off; off = (off + bytes + 255) & ~(size_t)255; return p;
  };
  int* csr_ptr = (int*)alloc((size_t)(N + 1) * 4);
  int* cursor  = (int*)alloc((size_t)N * 4);
  int* deg     = (int*)alloc((size_t)N * 4);
  int* bsum    = (int*)alloc(512 * 4);
  int* csr_src = (int*)alloc((size_t)ET * 4);
  float* xl1   = (float*)alloc((size_t)N * 16 * 4);
  float* xr1   = (float*)alloc((size_t)N * 16 * 4);
  float* h1    = (float*)alloc((size_t)N * 16 * 4);
  float* xl2   = (float*)alloc((size_t)N * 8 * 4);
  float* xr2   = (float*)alloc((size_t)N * 8 * 4);
  float* h2    = (float*)alloc((size_t)N * 8 * 4);
  float* gsum  = (float*)alloc((size_t)G * 8 * 4);
  float* gcnt  = (float*)alloc((size_t)G * 4);

  int nb = (N + 255) / 256;    // 391 <= 512

  k_init<<<(N + 255) / 256, 256, 0, stream>>>(deg, gsum, gcnt, N, G);
  k_hist<<<(E + 255) / 256, 256, 0, stream>>>(ei, deg, E);
  k_reduce<<<nb, 256, 0, stream>>>(deg, bsum, N);
  k_scan_bsum<<<1, 512, 0, stream>>>(bsum, nb);
  k_scan_final<<<nb, 256, 0, stream>>>(deg, bsum, csr_ptr, cursor, N);
  k_scatter<<<(ET + 255) / 256, 256, 0, stream>>>(ei, cursor, csr_src, E, N);
  k_gemm1<<<(N + 63) / 64, 256, 0, stream>>>(x, W1l, W1r, xl1, xr1, N);
  k_edge<16><<<(N + 15) / 16, 256, 0, stream>>>(csr_ptr, csr_src, xl1, xr1, a1, b1, h1, N);
  k_gemm2<<<(N + 255) / 256, 256, 0, stream>>>(h1, W2l, W2r, xl2, xr2, N);
  k_edge<8><<<(N + 31) / 32, 256, 0, stream>>>(csr_ptr, csr_src, xl2, xr2, a2, b2, h2, N);
  k_pool<<<(N + 255) / 256, 256, 0, stream>>>(h2, batch, gsum, gcnt, N);
  k_final<<<1, 256, 0, stream>>>(gsum, gcnt, Wlin, blin, out, G);
}

// Round 2
// 633.469 us; speedup vs baseline: 1.4517x; 1.4517x over previous
//
#include <hip/hip_runtime.h>
#include <hip/hip_bf16.h>
#include <math.h>

// ---------------- CSR build ----------------
__global__ void k_init(int* deg, int n) {
  int i = blockIdx.x * blockDim.x + threadIdx.x;
  if (i < n) deg[i] = 1;             // self loop contributes 1 to every node
}

__global__ void k_hist(const int* __restrict__ ei, int* deg, int E) {
  int i = blockIdx.x * blockDim.x + threadIdx.x;
  if (i < E) atomicAdd(&deg[ei[E + i]], 1);   // dst row of edge_index
}

__global__ void k_reduce(const int* __restrict__ deg, int* bsum, int n) {
  int i = blockIdx.x * 256 + threadIdx.x;
  int v = (i < n) ? deg[i] : 0;
  #pragma unroll
  for (int off = 32; off; off >>= 1) v += __shfl_down(v, off, 64);
  __shared__ int sh[4];
  if ((threadIdx.x & 63) == 0) sh[threadIdx.x >> 6] = v;
  __syncthreads();
  if (threadIdx.x == 0) bsum[blockIdx.x] = sh[0] + sh[1] + sh[2] + sh[3];
}

// single-block inclusive->exclusive scan of block sums (nb <= 512)
__global__ void k_scan_bsum(int* bsum, int nb) {
  __shared__ int sh[512];
  int t = threadIdx.x;
  int v = (t < nb) ? bsum[t] : 0;
  sh[t] = v; __syncthreads();
  for (int off = 1; off < 512; off <<= 1) {
    int add = (t >= off) ? sh[t - off] : 0;
    __syncthreads();
    sh[t] += add;
    __syncthreads();
  }
  if (t < nb) bsum[t] = sh[t] - v;   // exclusive
}

__global__ void k_scan_final(const int* __restrict__ deg, const int* __restrict__ bsum,
                             int* csr_ptr, int* cursor, int n) {
  __shared__ int sh[256];
  int t = threadIdx.x; int i = blockIdx.x * 256 + t;
  int v = (i < n) ? deg[i] : 0;
  sh[t] = v; __syncthreads();
  for (int off = 1; off < 256; off <<= 1) {
    int add = (t >= off) ? sh[t - off] : 0;
    __syncthreads();
    sh[t] += add;
    __syncthreads();
  }
  int excl = sh[t] - v + bsum[blockIdx.x];
  if (i < n) { csr_ptr[i] = excl; cursor[i] = excl; }
  if (i == n - 1) csr_ptr[n] = excl + v;
}

__global__ void k_scatter(const int* __restrict__ ei, int* cursor, int* csr_src,
                          int E, int n) {
  int i = blockIdx.x * blockDim.x + threadIdx.x;
  if (i >= E + n) return;
  int s, d;
  if (i < E) { s = ei[i]; d = ei[E + i]; } else { s = d = i - E; }
  int pos = atomicAdd(&cursor[d], 1);
  csr_src[pos] = s;
}

// ---------------- layer 1 transform: xl1 = x@W1l, xr1 = x@W1r ----------------
__global__ __launch_bounds__(256) void k_gemm1(const float* __restrict__ x,
    const float* __restrict__ Wl, const float* __restrict__ Wr,
    float* __restrict__ xl, float* __restrict__ xr, int n) {
  __shared__ float xs[64 * 132];     // 64 rows x 128, padded to 132 (bank spread)
  __shared__ float Ws[128 * 32];     // [k][c] c<16: Wl, c>=16: Wr
  int t = threadIdx.x;
  int r0 = blockIdx.x * 64;
  #pragma unroll
  for (int i = 0; i < 8; i++) {
    int idx = t + i * 256;           // 0..2047
    int k = idx >> 4, c = idx & 15;
    Ws[k * 32 + c]      = Wl[idx];
    Ws[k * 32 + 16 + c] = Wr[idx];
  }
  #pragma unroll
  for (int i = 0; i < 8; i++) {
    int v = t + i * 256;             // float4 units, 32 per row
    int row = v >> 5;
    int col4 = v & 31;
    float4 val = make_float4(0.f, 0.f, 0.f, 0.f);
    if (r0 + row < n)
      val = reinterpret_cast<const float4*>(x)[(long)(r0 + row) * 32 + col4];
    float* dst = &xs[row * 132 + col4 * 4];
    dst[0] = val.x; dst[1] = val.y; dst[2] = val.z; dst[3] = val.w;
  }
  __syncthreads();
  int g = t >> 2;                    // row in tile 0..63
  int sub = t & 3;                   // 8-col group
  float acc[8] = {0.f,0.f,0.f,0.f,0.f,0.f,0.f,0.f};
  #pragma unroll 4
  for (int k = 0; k < 128; k++) {
    float xv = xs[g * 132 + k];
    const float4* wp = reinterpret_cast<const float4*>(&Ws[k * 32 + sub * 8]);
    float4 w0 = wp[0], w1 = wp[1];
    acc[0] += xv * w0.x; acc[1] += xv * w0.y; acc[2] += xv * w0.z; acc[3] += xv * w0.w;
    acc[4] += xv * w1.x; acc[5] += xv * w1.y; acc[6] += xv * w1.z; acc[7] += xv * w1.w;
  }
  int row = r0 + g;
  if (row < n) {
    float* o = (sub < 2) ? &xl[(long)row * 16 + sub * 8]
                         : &xr[(long)row * 16 + (sub - 2) * 8];
    float4* o4 = reinterpret_cast<float4*>(o);
    o4[0] = make_float4(acc[0], acc[1], acc[2], acc[3]);
    o4[1] = make_float4(acc[4], acc[5], acc[6], acc[7]);
  }
}

// ---------------- layer 2 transform: xl2 = h@W2l, xr2 = h@W2r ----------------
__global__ void k_gemm2(const float* __restrict__ h,
    const float* __restrict__ Wl, const float* __restrict__ Wr,
    float* __restrict__ xl, float* __restrict__ xr, int n) {
  __shared__ float Wls[128], Wrs[128];
  int t = threadIdx.x;
  if (t < 128) { Wls[t] = Wl[t]; Wrs[t] = Wr[t]; }
  __syncthreads();
  int i = blockIdx.x * blockDim.x + t;
  if (i >= n) return;
  float hv[16];
  const float4* hp = reinterpret_cast<const float4*>(h + (long)i * 16);
  #pragma unroll
  for (int q = 0; q < 4; q++) {
    float4 v = hp[q];
    hv[q*4] = v.x; hv[q*4+1] = v.y; hv[q*4+2] = v.z; hv[q*4+3] = v.w;
  }
  float al[8] = {0,0,0,0,0,0,0,0}, ar[8] = {0,0,0,0,0,0,0,0};
  #pragma unroll
  for (int k = 0; k < 16; k++) {
    #pragma unroll
    for (int c = 0; c < 8; c++) {
      al[c] += hv[k] * Wls[k * 8 + c];
      ar[c] += hv[k] * Wrs[k * 8 + c];
    }
  }
  float4* xlp = reinterpret_cast<float4*>(xl + (long)i * 8);
  float4* xrp = reinterpret_cast<float4*>(xr + (long)i * 8);
  xlp[0] = make_float4(al[0], al[1], al[2], al[3]);
  xlp[1] = make_float4(al[4], al[5], al[6], al[7]);
  xrp[0] = make_float4(ar[0], ar[1], ar[2], ar[3]);
  xrp[1] = make_float4(ar[4], ar[5], ar[6], ar[7]);
}

// ------------- pull-style GATv2 aggregation, online softmax, C lanes/node -------------
template<int C>
__global__ __launch_bounds__(256) void k_edge(const int* __restrict__ csr_ptr,
    const int* __restrict__ csr_src, const float* __restrict__ xl,
    const float* __restrict__ xr, const float* __restrict__ att,
    const float* __restrict__ bias, float* __restrict__ out, int n) {
  int t = threadIdx.x;
  const int gpb = 256 / C;
  int node = blockIdx.x * gpb + t / C;
  int c = t % C;
  if (node >= n) return;
  int beg = csr_ptr[node], end = csr_ptr[node + 1];
  float xr_c = xr[(long)node * C + c];
  float a_c = att[c];
  float m = -INFINITY, s = 0.f, num = 0.f;
  for (int i = beg; i < end; ++i) {
    int src = csr_src[i];
    float xl_c = xl[(long)src * C + c];
    float v = xl_c + xr_c;
    v = (v > 0.f) ? v : 0.2f * v;          // leaky_relu 0.2
    float p = v * a_c;
    #pragma unroll
    for (int off = C / 2; off > 0; off >>= 1) p += __shfl_xor(p, off, 64);
    float e = p;                            // all C lanes hold edge score
    float mn = fmaxf(m, e);
    float sc = __expf(m - mn);              // first iter: exp(-inf)=0
    float pe = __expf(e - mn);
    s = s * sc + pe;
    num = num * sc + pe * xl_c;
    m = mn;
  }
  float o = num / fmaxf(s, 1e-16f) + bias[c];
  out[(long)node * C + c] = fmaxf(o, 0.f);  // relu (both layers use relu)
}

// ---------------- fused mean pool + linear: one block per graph ----------------
// batch is sorted, so graph g's nodes are a contiguous range found by binary search.
// mean(h) @ Wlin == mean(h @ Wlin), so each thread accumulates h[i].Wlin scalars.
__global__ __launch_bounds__(256) void k_pool_final(const float* __restrict__ h,
    const int* __restrict__ batch, const float* __restrict__ Wlin,
    const float* __restrict__ blin, float* __restrict__ out, int n) {
  int g = blockIdx.x;
  // lower_bound(batch, g) and lower_bound(batch, g+1)
  int lo = 0, hi = n;
  while (lo < hi) { int mid = (lo + hi) >> 1; if (batch[mid] < g) lo = mid + 1; else hi = mid; }
  int beg = lo;
  hi = n;
  while (lo < hi) { int mid = (lo + hi) >> 1; if (batch[mid] < g + 1) lo = mid + 1; else hi = mid; }
  int end = lo;

  float w[8];
  #pragma unroll
  for (int c = 0; c < 8; c++) w[c] = Wlin[c];

  float acc = 0.f;
  int t = threadIdx.x;
  for (int i = beg + t; i < end; i += 256) {
    const float4* hp = reinterpret_cast<const float4*>(h + (long)i * 8);
    float4 v0 = hp[0], v1 = hp[1];
    acc += v0.x * w[0] + v0.y * w[1] + v0.z * w[2] + v0.w * w[3]
         + v1.x * w[4] + v1.y * w[5] + v1.z * w[6] + v1.w * w[7];
  }
  // block reduction
  #pragma unroll
  for (int off = 32; off; off >>= 1) acc += __shfl_down(acc, off, 64);
  __shared__ float sh[4];
  if ((t & 63) == 0) sh[t >> 6] = acc;
  __syncthreads();
  if (t == 0) {
    float total = sh[0] + sh[1] + sh[2] + sh[3];
    float cnt = (float)(end - beg);
    out[g] = total / fmaxf(cnt, 1.f) + blin[0];
  }
}

extern "C" void kernel_launch(void* const* d_in, const int* in_sizes, int n_in,
                              void* d_out, int out_size, void* d_ws, size_t ws_size,
                              hipStream_t stream) {
  (void)n_in; (void)ws_size;
  const float* x    = (const float*)d_in[0];
  const int*   ei   = (const int*)d_in[1];
  const int*   batch= (const int*)d_in[2];
  const float* W1l  = (const float*)d_in[3];
  const float* W1r  = (const float*)d_in[4];
  const float* a1   = (const float*)d_in[5];
  const float* b1   = (const float*)d_in[6];
  const float* W2l  = (const float*)d_in[7];
  const float* W2r  = (const float*)d_in[8];
  const float* a2   = (const float*)d_in[9];
  const float* b2   = (const float*)d_in[10];
  const float* Wlin = (const float*)d_in[11];
  const float* blin = (const float*)d_in[12];
  float* out = (float*)d_out;

  int N = in_sizes[0] / 128;
  int E = in_sizes[1] / 2;
  int G = out_size;            // 256 graphs, output [G,1]
  int ET = E + N;              // edges incl self loops

  char* ws = (char*)d_ws;
  size_t off = 0;
  auto alloc = [&](size_t bytes) {
    void* p = ws + off; off = (off + bytes + 255) & ~(size_t)255; return p;
  };
  int* csr_ptr = (int*)alloc((size_t)(N + 1) * 4);
  int* cursor  = (int*)alloc((size_t)N * 4);
  int* deg     = (int*)alloc((size_t)N * 4);
  int* bsum    = (int*)alloc(512 * 4);
  int* csr_src = (int*)alloc((size_t)ET * 4);
  float* xl1   = (float*)alloc((size_t)N * 16 * 4);
  float* xr1   = (float*)alloc((size_t)N * 16 * 4);
  float* h1    = (float*)alloc((size_t)N * 16 * 4);
  float* xl2   = (float*)alloc((size_t)N * 8 * 4);
  float* xr2   = (float*)alloc((size_t)N * 8 * 4);
  float* h2    = (float*)alloc((size_t)N * 8 * 4);

  int nb = (N + 255) / 256;    // 391 <= 512

  k_init<<<(N + 255) / 256, 256, 0, stream>>>(deg, N);
  k_hist<<<(E + 255) / 256, 256, 0, stream>>>(ei, deg, E);
  k_reduce<<<nb, 256, 0, stream>>>(deg, bsum, N);
  k_scan_bsum<<<1, 512, 0, stream>>>(bsum, nb);
  k_scan_final<<<nb, 256, 0, stream>>>(deg, bsum, csr_ptr, cursor, N);
  k_scatter<<<(ET + 255) / 256, 256, 0, stream>>>(ei, cursor, csr_src, E, N);
  k_gemm1<<<(N + 63) / 64, 256, 0, stream>>>(x, W1l, W1r, xl1, xr1, N);
  k_edge<16><<<(N + 15) / 16, 256, 0, stream>>>(csr_ptr, csr_src, xl1, xr1, a1, b1, h1, N);
  k_gemm2<<<(N + 255) / 256, 256, 0, stream>>>(h1, W2l, W2r, xl2, xr2, N);
  k_edge<8><<<(N + 31) / 32, 256, 0, stream>>>(csr_ptr, csr_src, xl2, xr2, a2, b2, h2, N);
  k_pool_final<<<G, 256, 0, stream>>>(h2, batch, Wlin, blin, out, N);
}

// Round 3
// 298.081 us; speedup vs baseline: 3.0851x; 2.1252x over previous
//
#include <hip/hip_runtime.h>
#include <hip/hip_bf16.h>
#include <math.h>

#define NBLK 256   // binning blocks
#define NB   512   // dst buckets

// ---------------- binned CSR build (no global atomics) ----------------
__global__ __launch_bounds__(256) void k_bin_count(const int* __restrict__ ei,
    int E, int ET, int BW, int chunk, int* __restrict__ A) {
  __shared__ int lh[NB];
  int t = threadIdx.x;
  lh[t] = 0; lh[t + 256] = 0;
  __syncthreads();
  int beg = blockIdx.x * chunk, end = min(beg + chunk, ET);
  for (int i = beg + t; i < end; i += 256) {
    int d = (i < E) ? ei[E + i] : (i - E);      // self loop for i>=E
    atomicAdd(&lh[d / BW], 1);
  }
  __syncthreads();
  A[t * NBLK + blockIdx.x] = lh[t];
  A[(t + 256) * NBLK + blockIdx.x] = lh[t + 256];
}

__global__ void k_reduce(const int* __restrict__ a, int* bsum, int n) {
  int i = blockIdx.x * 256 + threadIdx.x;
  int v = (i < n) ? a[i] : 0;
  #pragma unroll
  for (int off = 32; off; off >>= 1) v += __shfl_down(v, off, 64);
  __shared__ int sh[4];
  if ((threadIdx.x & 63) == 0) sh[threadIdx.x >> 6] = v;
  __syncthreads();
  if (threadIdx.x == 0) bsum[blockIdx.x] = sh[0] + sh[1] + sh[2] + sh[3];
}

// single-block inclusive->exclusive scan of block sums (nb <= 512)
__global__ void k_scan_bsum(int* bsum, int nb) {
  __shared__ int sh[512];
  int t = threadIdx.x;
  int v = (t < nb) ? bsum[t] : 0;
  sh[t] = v; __syncthreads();
  for (int off = 1; off < 512; off <<= 1) {
    int add = (t >= off) ? sh[t - off] : 0;
    __syncthreads();
    sh[t] += add;
    __syncthreads();
  }
  if (t < nb) bsum[t] = sh[t] - v;   // exclusive
}

// in-place exclusive scan apply; writes A[n] = total
__global__ void k_scan_apply(int* A, const int* __restrict__ bsum, int n) {
  __shared__ int sh[256];
  int t = threadIdx.x; int i = blockIdx.x * 256 + t;
  int v = (i < n) ? A[i] : 0;
  sh[t] = v; __syncthreads();
  for (int off = 1; off < 256; off <<= 1) {
    int add = (t >= off) ? sh[t - off] : 0;
    __syncthreads();
    sh[t] += add;
    __syncthreads();
  }
  int excl = sh[t] - v + bsum[blockIdx.x];
  if (i < n) A[i] = excl;
  if (i == n - 1) A[n] = excl + v;
}

__global__ __launch_bounds__(256) void k_bin_scatter(const int* __restrict__ ei,
    int E, int ET, int BW, int chunk, const int* __restrict__ A, int2* __restrict__ pairs) {
  __shared__ int cur[NB];
  int t = threadIdx.x;
  cur[t]       = A[t * NBLK + blockIdx.x];
  cur[t + 256] = A[(t + 256) * NBLK + blockIdx.x];
  __syncthreads();
  int beg = blockIdx.x * chunk, end = min(beg + chunk, ET);
  for (int i = beg + t; i < end; i += 256) {
    int s, d;
    if (i < E) { s = ei[i]; d = ei[E + i]; } else { s = d = i - E; }
    int pos = atomicAdd(&cur[d / BW], 1);
    pairs[pos] = make_int2(s, d);
  }
}

__global__ __launch_bounds__(256) void k_csr_build(const int2* __restrict__ pairs,
    const int* __restrict__ A, int* __restrict__ csr_ptr, int* __restrict__ csr_src,
    int BW, int N, int ET) {
  __shared__ int cnt[256];
  __shared__ int cur[256];
  __shared__ int sh[256];
  int b = blockIdx.x, t = threadIdx.x;
  int base = A[b * NBLK], endp = A[(b + 1) * NBLK];
  int node0 = b * BW;
  cnt[t] = 0;
  __syncthreads();
  for (int e = base + t; e < endp; e += 256)
    atomicAdd(&cnt[pairs[e].y - node0], 1);
  __syncthreads();
  int v = cnt[t];
  sh[t] = v; __syncthreads();
  for (int off = 1; off < 256; off <<= 1) {
    int add = (t >= off) ? sh[t - off] : 0;
    __syncthreads();
    sh[t] += add;
    __syncthreads();
  }
  int excl = sh[t] - v;
  if (t < BW && node0 + t < N) csr_ptr[node0 + t] = base + excl;
  cur[t] = base + excl;
  if (b == (int)gridDim.x - 1 && t == 0) csr_ptr[N] = endp;
  __syncthreads();
  for (int e = base + t; e < endp; e += 256) {
    int2 p = pairs[e];
    int pos = atomicAdd(&cur[p.y - node0], 1);
    csr_src[pos] = p.x;
  }
}

// ---------------- layer 1 transform: xl1 = x@W1l, xr1 = x@W1r ----------------
__global__ __launch_bounds__(256) void k_gemm1(const float* __restrict__ x,
    const float* __restrict__ Wl, const float* __restrict__ Wr,
    float* __restrict__ xl, float* __restrict__ xr, int n) {
  __shared__ float xs[64 * 132];     // 64 rows x 128, padded to 132 (bank spread)
  __shared__ float Ws[128 * 32];     // [k][c] c<16: Wl, c>=16: Wr
  int t = threadIdx.x;
  int r0 = blockIdx.x * 64;
  #pragma unroll
  for (int i = 0; i < 8; i++) {
    int idx = t + i * 256;           // 0..2047
    int k = idx >> 4, c = idx & 15;
    Ws[k * 32 + c]      = Wl[idx];
    Ws[k * 32 + 16 + c] = Wr[idx];
  }
  #pragma unroll
  for (int i = 0; i < 8; i++) {
    int v = t + i * 256;             // float4 units, 32 per row
    int row = v >> 5;
    int col4 = v & 31;
    float4 val = make_float4(0.f, 0.f, 0.f, 0.f);
    if (r0 + row < n)
      val = reinterpret_cast<const float4*>(x)[(long)(r0 + row) * 32 + col4];
    float* dst = &xs[row * 132 + col4 * 4];
    dst[0] = val.x; dst[1] = val.y; dst[2] = val.z; dst[3] = val.w;
  }
  __syncthreads();
  int g = t >> 2;                    // row in tile 0..63
  int sub = t & 3;                   // 8-col group
  float acc[8] = {0.f,0.f,0.f,0.f,0.f,0.f,0.f,0.f};
  #pragma unroll 4
  for (int k = 0; k < 128; k++) {
    float xv = xs[g * 132 + k];
    const float4* wp = reinterpret_cast<const float4*>(&Ws[k * 32 + sub * 8]);
    float4 w0 = wp[0], w1 = wp[1];
    acc[0] += xv * w0.x; acc[1] += xv * w0.y; acc[2] += xv * w0.z; acc[3] += xv * w0.w;
    acc[4] += xv * w1.x; acc[5] += xv * w1.y; acc[6] += xv * w1.z; acc[7] += xv * w1.w;
  }
  int row = r0 + g;
  if (row < n) {
    float* o = (sub < 2) ? &xl[(long)row * 16 + sub * 8]
                         : &xr[(long)row * 16 + (sub - 2) * 8];
    float4* o4 = reinterpret_cast<float4*>(o);
    o4[0] = make_float4(acc[0], acc[1], acc[2], acc[3]);
    o4[1] = make_float4(acc[4], acc[5], acc[6], acc[7]);
  }
}

// ---------------- layer 2 transform: xl2 = h@W2l, xr2 = h@W2r ----------------
__global__ void k_gemm2(const float* __restrict__ h,
    const float* __restrict__ Wl, const float* __restrict__ Wr,
    float* __restrict__ xl, float* __restrict__ xr, int n) {
  __shared__ float Wls[128], Wrs[128];
  int t = threadIdx.x;
  if (t < 128) { Wls[t] = Wl[t]; Wrs[t] = Wr[t]; }
  __syncthreads();
  int i = blockIdx.x * blockDim.x + t;
  if (i >= n) return;
  float hv[16];
  const float4* hp = reinterpret_cast<const float4*>(h + (long)i * 16);
  #pragma unroll
  for (int q = 0; q < 4; q++) {
    float4 v = hp[q];
    hv[q*4] = v.x; hv[q*4+1] = v.y; hv[q*4+2] = v.z; hv[q*4+3] = v.w;
  }
  float al[8] = {0,0,0,0,0,0,0,0}, ar[8] = {0,0,0,0,0,0,0,0};
  #pragma unroll
  for (int k = 0; k < 16; k++) {
    #pragma unroll
    for (int c = 0; c < 8; c++) {
      al[c] += hv[k] * Wls[k * 8 + c];
      ar[c] += hv[k] * Wrs[k * 8 + c];
    }
  }
  float4* xlp = reinterpret_cast<float4*>(xl + (long)i * 8);
  float4* xrp = reinterpret_cast<float4*>(xr + (long)i * 8);
  xlp[0] = make_float4(al[0], al[1], al[2], al[3]);
  xlp[1] = make_float4(al[4], al[5], al[6], al[7]);
  xrp[0] = make_float4(ar[0], ar[1], ar[2], ar[3]);
  xrp[1] = make_float4(ar[4], ar[5], ar[6], ar[7]);
}

// ------------- pull-style GATv2 aggregation, online softmax, C lanes/node -------------
template<int C>
__global__ __launch_bounds__(256) void k_edge(const int* __restrict__ csr_ptr,
    const int* __restrict__ csr_src, const float* __restrict__ xl,
    const float* __restrict__ xr, const float* __restrict__ att,
    const float* __restrict__ bias, float* __restrict__ out, int n) {
  int t = threadIdx.x;
  const int gpb = 256 / C;
  int node = blockIdx.x * gpb + t / C;
  int c = t % C;
  if (node >= n) return;
  int beg = csr_ptr[node], end = csr_ptr[node + 1];
  float xr_c = xr[(long)node * C + c];
  float a_c = att[c];
  float m = -INFINITY, s = 0.f, num = 0.f;
  for (int i = beg; i < end; ++i) {
    int src = csr_src[i];
    float xl_c = xl[(long)src * C + c];
    float v = xl_c + xr_c;
    v = (v > 0.f) ? v : 0.2f * v;          // leaky_relu 0.2
    float p = v * a_c;
    #pragma unroll
    for (int off = C / 2; off > 0; off >>= 1) p += __shfl_xor(p, off, 64);
    float e = p;                            // all C lanes hold edge score
    float mn = fmaxf(m, e);
    float sc = __expf(m - mn);              // first iter: exp(-inf)=0
    float pe = __expf(e - mn);
    s = s * sc + pe;
    num = num * sc + pe * xl_c;
    m = mn;
  }
  float o = num / fmaxf(s, 1e-16f) + bias[c];
  out[(long)node * C + c] = fmaxf(o, 0.f);  // relu (both layers use relu)
}

// ---------------- fused mean pool + linear: one block per graph ----------------
__global__ __launch_bounds__(256) void k_pool_final(const float* __restrict__ h,
    const int* __restrict__ batch, const float* __restrict__ Wlin,
    const float* __restrict__ blin, float* __restrict__ out, int n) {
  int g = blockIdx.x;
  int lo = 0, hi = n;
  while (lo < hi) { int mid = (lo + hi) >> 1; if (batch[mid] < g) lo = mid + 1; else hi = mid; }
  int beg = lo;
  hi = n;
  while (lo < hi) { int mid = (lo + hi) >> 1; if (batch[mid] < g + 1) lo = mid + 1; else hi = mid; }
  int end = lo;

  float w[8];
  #pragma unroll
  for (int c = 0; c < 8; c++) w[c] = Wlin[c];

  float acc = 0.f;
  int t = threadIdx.x;
  for (int i = beg + t; i < end; i += 256) {
    const float4* hp = reinterpret_cast<const float4*>(h + (long)i * 8);
    float4 v0 = hp[0], v1 = hp[1];
    acc += v0.x * w[0] + v0.y * w[1] + v0.z * w[2] + v0.w * w[3]
         + v1.x * w[4] + v1.y * w[5] + v1.z * w[6] + v1.w * w[7];
  }
  #pragma unroll
  for (int off = 32; off; off >>= 1) acc += __shfl_down(acc, off, 64);
  __shared__ float sh[4];
  if ((t & 63) == 0) sh[t >> 6] = acc;
  __syncthreads();
  if (t == 0) {
    float total = sh[0] + sh[1] + sh[2] + sh[3];
    float cnt = (float)(end - beg);
    out[g] = total / fmaxf(cnt, 1.f) + blin[0];
  }
}

extern "C" void kernel_launch(void* const* d_in, const int* in_sizes, int n_in,
                              void* d_out, int out_size, void* d_ws, size_t ws_size,
                              hipStream_t stream) {
  (void)n_in; (void)ws_size;
  const float* x    = (const float*)d_in[0];
  const int*   ei   = (const int*)d_in[1];
  const int*   batch= (const int*)d_in[2];
  const float* W1l  = (const float*)d_in[3];
  const float* W1r  = (const float*)d_in[4];
  const float* a1   = (const float*)d_in[5];
  const float* b1   = (const float*)d_in[6];
  const float* W2l  = (const float*)d_in[7];
  const float* W2r  = (const float*)d_in[8];
  const float* a2   = (const float*)d_in[9];
  const float* b2   = (const float*)d_in[10];
  const float* Wlin = (const float*)d_in[11];
  const float* blin = (const float*)d_in[12];
  float* out = (float*)d_out;

  int N = in_sizes[0] / 128;
  int E = in_sizes[1] / 2;
  int G = out_size;            // 256 graphs
  int ET = E + N;              // edges incl self loops
  int BW = (N + NB - 1) / NB;  // nodes per bucket
  int chunk = (ET + NBLK - 1) / NBLK;
  int nA = NB * NBLK;          // 131072

  char* ws = (char*)d_ws;
  size_t off = 0;
  auto alloc = [&](size_t bytes) {
    void* p = ws + off; off = (off + bytes + 255) & ~(size_t)255; return p;
  };
  int* csr_ptr = (int*)alloc((size_t)(N + 1) * 4);
  int* A       = (int*)alloc((size_t)(nA + 1) * 4);
  int* bsum    = (int*)alloc(512 * 4);
  int* csr_src = (int*)alloc((size_t)ET * 4);
  // union: pairs (ET*8 B) time-shared with feature buffers (N*288 B)
  size_t featBytes = (size_t)N * (16 + 16 + 16 + 8 + 8 + 8) * 4;
  size_t pairBytes = (size_t)ET * 8;
  char* u = (char*)alloc(pairBytes > featBytes ? pairBytes : featBytes);
  int2* pairs = (int2*)u;
  float* xl1 = (float*)u;
  float* xr1 = xl1 + (size_t)N * 16;
  float* h1  = xr1 + (size_t)N * 16;
  float* xl2 = h1  + (size_t)N * 16;
  float* xr2 = xl2 + (size_t)N * 8;
  float* h2  = xr2 + (size_t)N * 8;

  k_bin_count<<<NBLK, 256, 0, stream>>>(ei, E, ET, BW, chunk, A);
  k_reduce<<<(nA + 255) / 256, 256, 0, stream>>>(A, bsum, nA);
  k_scan_bsum<<<1, 512, 0, stream>>>(bsum, (nA + 255) / 256);
  k_scan_apply<<<(nA + 255) / 256, 256, 0, stream>>>(A, bsum, nA);
  k_bin_scatter<<<NBLK, 256, 0, stream>>>(ei, E, ET, BW, chunk, A, pairs);
  k_csr_build<<<NB, 256, 0, stream>>>(pairs, A, csr_ptr, csr_src, BW, N, ET);
  k_gemm1<<<(N + 63) / 64, 256, 0, stream>>>(x, W1l, W1r, xl1, xr1, N);
  k_edge<16><<<(N + 15) / 16, 256, 0, stream>>>(csr_ptr, csr_src, xl1, xr1, a1, b1, h1, N);
  k_gemm2<<<(N + 255) / 256, 256, 0, stream>>>(h1, W2l, W2r, xl2, xr2, N);
  k_edge<8><<<(N + 31) / 32, 256, 0, stream>>>(csr_ptr, csr_src, xl2, xr2, a2, b2, h2, N);
  k_pool_final<<<G, 256, 0, stream>>>(h2, batch, Wlin, blin, out, N);
}

// Round 4
// 209.552 us; speedup vs baseline: 4.3884x; 1.4225x over previous
//
#include <hip/hip_runtime.h>
#include <hip/hip_bf16.h>
#include <math.h>

#define NBLK 256   // binning blocks
#define NB   512   // dst buckets

// ---------------- binned CSR build (no global atomics) ----------------
__global__ __launch_bounds__(256) void k_bin_count(const int* __restrict__ ei,
    int E, int ET, int BW, int chunk, int* __restrict__ A) {
  __shared__ int lh[NB];
  int t = threadIdx.x;
  lh[t] = 0; lh[t + 256] = 0;
  __syncthreads();
  int beg = blockIdx.x * chunk, end = min(beg + chunk, ET);
  for (int i = beg + t; i < end; i += 256) {
    int d = (i < E) ? ei[E + i] : (i - E);      // self loop for i>=E
    atomicAdd(&lh[d / BW], 1);
  }
  __syncthreads();
  A[t * NBLK + blockIdx.x] = lh[t];
  A[(t + 256) * NBLK + blockIdx.x] = lh[t + 256];
}

__global__ void k_reduce(const int* __restrict__ a, int* bsum, int n) {
  int i = blockIdx.x * 256 + threadIdx.x;
  int v = (i < n) ? a[i] : 0;
  #pragma unroll
  for (int off = 32; off; off >>= 1) v += __shfl_down(v, off, 64);
  __shared__ int sh[4];
  if ((threadIdx.x & 63) == 0) sh[threadIdx.x >> 6] = v;
  __syncthreads();
  if (threadIdx.x == 0) bsum[blockIdx.x] = sh[0] + sh[1] + sh[2] + sh[3];
}

// single-block inclusive->exclusive scan of block sums (nb <= 512)
__global__ void k_scan_bsum(int* bsum, int nb) {
  __shared__ int sh[512];
  int t = threadIdx.x;
  int v = (t < nb) ? bsum[t] : 0;
  sh[t] = v; __syncthreads();
  for (int off = 1; off < 512; off <<= 1) {
    int add = (t >= off) ? sh[t - off] : 0;
    __syncthreads();
    sh[t] += add;
    __syncthreads();
  }
  if (t < nb) bsum[t] = sh[t] - v;   // exclusive
}

// in-place exclusive scan apply; writes A[n] = total
__global__ void k_scan_apply(int* A, const int* __restrict__ bsum, int n) {
  __shared__ int sh[256];
  int t = threadIdx.x; int i = blockIdx.x * 256 + t;
  int v = (i < n) ? A[i] : 0;
  sh[t] = v; __syncthreads();
  for (int off = 1; off < 256; off <<= 1) {
    int add = (t >= off) ? sh[t - off] : 0;
    __syncthreads();
    sh[t] += add;
    __syncthreads();
  }
  int excl = sh[t] - v + bsum[blockIdx.x];
  if (i < n) A[i] = excl;
  if (i == n - 1) A[n] = excl + v;
}

__global__ __launch_bounds__(256) void k_bin_scatter(const int* __restrict__ ei,
    int E, int ET, int BW, int chunk, const int* __restrict__ A, int2* __restrict__ pairs) {
  __shared__ int cur[NB];
  int t = threadIdx.x;
  cur[t]       = A[t * NBLK + blockIdx.x];
  cur[t + 256] = A[(t + 256) * NBLK + blockIdx.x];
  __syncthreads();
  int beg = blockIdx.x * chunk, end = min(beg + chunk, ET);
  for (int i = beg + t; i < end; i += 256) {
    int s, d;
    if (i < E) { s = ei[i]; d = ei[E + i]; } else { s = d = i - E; }
    int pos = atomicAdd(&cur[d / BW], 1);
    pairs[pos] = make_int2(s, d);
  }
}

__global__ __launch_bounds__(256) void k_csr_build(const int2* __restrict__ pairs,
    const int* __restrict__ A, int* __restrict__ csr_ptr, int* __restrict__ csr_src,
    int BW, int N, int ET) {
  __shared__ int cnt[256];
  __shared__ int cur[256];
  __shared__ int sh[256];
  int b = blockIdx.x, t = threadIdx.x;
  int base = A[b * NBLK], endp = A[(b + 1) * NBLK];
  int node0 = b * BW;
  cnt[t] = 0;
  __syncthreads();
  for (int e = base + t; e < endp; e += 256)
    atomicAdd(&cnt[pairs[e].y - node0], 1);
  __syncthreads();
  int v = cnt[t];
  sh[t] = v; __syncthreads();
  for (int off = 1; off < 256; off <<= 1) {
    int add = (t >= off) ? sh[t - off] : 0;
    __syncthreads();
    sh[t] += add;
    __syncthreads();
  }
  int excl = sh[t] - v;
  if (t < BW && node0 + t < N) csr_ptr[node0 + t] = base + excl;
  cur[t] = base + excl;
  if (b == (int)gridDim.x - 1 && t == 0) csr_ptr[N] = endp;
  __syncthreads();
  for (int e = base + t; e < endp; e += 256) {
    int2 p = pairs[e];
    int pos = atomicAdd(&cur[p.y - node0], 1);
    csr_src[pos] = p.x;
  }
}

// ---------------- layer 1 transform: xl1 = x@W1l, xr1 = x@W1r ----------------
__global__ __launch_bounds__(256) void k_gemm1(const float* __restrict__ x,
    const float* __restrict__ Wl, const float* __restrict__ Wr,
    float* __restrict__ xl, float* __restrict__ xr, int n) {
  __shared__ float xs[64 * 132];     // 64 rows x 128, padded to 132 (bank spread)
  __shared__ float Ws[128 * 32];     // [k][c] c<16: Wl, c>=16: Wr
  int t = threadIdx.x;
  int r0 = blockIdx.x * 64;
  #pragma unroll
  for (int i = 0; i < 8; i++) {
    int idx = t + i * 256;           // 0..2047
    int k = idx >> 4, c = idx & 15;
    Ws[k * 32 + c]      = Wl[idx];
    Ws[k * 32 + 16 + c] = Wr[idx];
  }
  #pragma unroll
  for (int i = 0; i < 8; i++) {
    int v = t + i * 256;             // float4 units, 32 per row
    int row = v >> 5;
    int col4 = v & 31;
    float4 val = make_float4(0.f, 0.f, 0.f, 0.f);
    if (r0 + row < n)
      val = reinterpret_cast<const float4*>(x)[(long)(r0 + row) * 32 + col4];
    float* dst = &xs[row * 132 + col4 * 4];
    dst[0] = val.x; dst[1] = val.y; dst[2] = val.z; dst[3] = val.w;
  }
  __syncthreads();
  int g = t >> 2;                    // row in tile 0..63
  int sub = t & 3;                   // 8-col group
  float acc[8] = {0.f,0.f,0.f,0.f,0.f,0.f,0.f,0.f};
  #pragma unroll 4
  for (int k = 0; k < 128; k++) {
    float xv = xs[g * 132 + k];
    const float4* wp = reinterpret_cast<const float4*>(&Ws[k * 32 + sub * 8]);
    float4 w0 = wp[0], w1 = wp[1];
    acc[0] += xv * w0.x; acc[1] += xv * w0.y; acc[2] += xv * w0.z; acc[3] += xv * w0.w;
    acc[4] += xv * w1.x; acc[5] += xv * w1.y; acc[6] += xv * w1.z; acc[7] += xv * w1.w;
  }
  int row = r0 + g;
  if (row < n) {
    float* o = (sub < 2) ? &xl[(long)row * 16 + sub * 8]
                         : &xr[(long)row * 16 + (sub - 2) * 8];
    float4* o4 = reinterpret_cast<float4*>(o);
    o4[0] = make_float4(acc[0], acc[1], acc[2], acc[3]);
    o4[1] = make_float4(acc[4], acc[5], acc[6], acc[7]);
  }
}

// ---------------- layer 2 transform: xl2 = h@W2l, xr2 = h@W2r ----------------
__global__ void k_gemm2(const float* __restrict__ h,
    const float* __restrict__ Wl, const float* __restrict__ Wr,
    float* __restrict__ xl, float* __restrict__ xr, int n) {
  __shared__ float Wls[128], Wrs[128];
  int t = threadIdx.x;
  if (t < 128) { Wls[t] = Wl[t]; Wrs[t] = Wr[t]; }
  __syncthreads();
  int i = blockIdx.x * blockDim.x + t;
  if (i >= n) return;
  float hv[16];
  const float4* hp = reinterpret_cast<const float4*>(h + (long)i * 16);
  #pragma unroll
  for (int q = 0; q < 4; q++) {
    float4 v = hp[q];
    hv[q*4] = v.x; hv[q*4+1] = v.y; hv[q*4+2] = v.z; hv[q*4+3] = v.w;
  }
  float al[8] = {0,0,0,0,0,0,0,0}, ar[8] = {0,0,0,0,0,0,0,0};
  #pragma unroll
  for (int k = 0; k < 16; k++) {
    #pragma unroll
    for (int c = 0; c < 8; c++) {
      al[c] += hv[k] * Wls[k * 8 + c];
      ar[c] += hv[k] * Wrs[k * 8 + c];
    }
  }
  float4* xlp = reinterpret_cast<float4*>(xl + (long)i * 8);
  float4* xrp = reinterpret_cast<float4*>(xr + (long)i * 8);
  xlp[0] = make_float4(al[0], al[1], al[2], al[3]);
  xlp[1] = make_float4(al[4], al[5], al[6], al[7]);
  xrp[0] = make_float4(ar[0], ar[1], ar[2], ar[3]);
  xrp[1] = make_float4(ar[4], ar[5], ar[6], ar[7]);
}

// ---------------- DPP cross-lane reduction (VALU, no LDS/DS ops) ----------------
// quad_perm 0xB1 = lanes [1,0,3,2] (xor 1); 0x4E = [2,3,0,1] (xor 2);
// 0x141 = row_half_mirror (== xor 4 once quads are homogeneous);
// 0x140 = row_mirror (== xor 8 once octets are homogeneous).
template<int CTRL>
__device__ __forceinline__ float dpp_add(float x) {
  int y = __builtin_amdgcn_update_dpp(0, __float_as_int(x), CTRL, 0xF, 0xF, true);
  return x + __int_as_float(y);
}

template<int C>
__device__ __forceinline__ float group_reduce(float x) {
  x = dpp_add<0xB1>(x);
  x = dpp_add<0x4E>(x);
  x = dpp_add<0x141>(x);
  if (C == 16) x = dpp_add<0x140>(x);
  return x;
}

// ------------- pull-style GATv2 aggregation, defer-max softmax, C lanes/node -------------
// U independent accumulator chains for ILP; m starts at 0 and only rescales if a
// score exceeds m+25 (exact general fallback; exp headroom: s <= deg*exp(25) << f32 max).
template<int C, int U>
__global__ __launch_bounds__(256) void k_edge(const int* __restrict__ csr_ptr,
    const int* __restrict__ csr_src, const float* __restrict__ xl,
    const float* __restrict__ xr, const float* __restrict__ att,
    const float* __restrict__ bias, float* __restrict__ out, int n) {
  int t = threadIdx.x;
  int node = blockIdx.x * (256 / C) + t / C;
  int c = t % C;
  if (node >= n) return;
  int beg = csr_ptr[node], end = csr_ptr[node + 1];
  float xr_c = xr[(long)node * C + c];
  float a_c = att[c];
  float m[U], s[U], nu[U];
  #pragma unroll
  for (int u = 0; u < U; u++) { m[u] = 0.f; s[u] = 0.f; nu[u] = 0.f; }
  int i = beg;
  for (; i + U <= end; i += U) {
    float xlv[U], e[U];
    #pragma unroll
    for (int u = 0; u < U; u++) {
      int src = csr_src[i + u];
      xlv[u] = xl[(long)src * C + c];
    }
    #pragma unroll
    for (int u = 0; u < U; u++) {
      float v = xlv[u] + xr_c;
      v = (v > 0.f) ? v : 0.2f * v;          // leaky_relu 0.2
      e[u] = group_reduce<C>(v * a_c);
    }
    #pragma unroll
    for (int u = 0; u < U; u++) {
      if (e[u] > m[u] + 25.f) {              // rare: exact rescale fallback
        float sc = __expf(m[u] - e[u]);
        s[u] *= sc; nu[u] *= sc; m[u] = e[u];
      }
      float pe = __expf(e[u] - m[u]);
      s[u] += pe;
      nu[u] += pe * xlv[u];
    }
  }
  for (; i < end; ++i) {
    int src = csr_src[i];
    float xlv = xl[(long)src * C + c];
    float v = xlv + xr_c;
    v = (v > 0.f) ? v : 0.2f * v;
    float e = group_reduce<C>(v * a_c);
    if (e > m[0] + 25.f) {
      float sc = __expf(m[0] - e);
      s[0] *= sc; nu[0] *= sc; m[0] = e;
    }
    float pe = __expf(e - m[0]);
    s[0] += pe;
    nu[0] += pe * xlv;
  }
  // merge chains (exact)
  float M = m[0], S = s[0], NU = nu[0];
  #pragma unroll
  for (int u = 1; u < U; u++) {
    float mn = fmaxf(M, m[u]);
    float sc0 = __expf(M - mn), sc1 = __expf(m[u] - mn);
    S = S * sc0 + s[u] * sc1;
    NU = NU * sc0 + nu[u] * sc1;
    M = mn;
  }
  float o = NU / fmaxf(S, 1e-16f) + bias[c];
  out[(long)node * C + c] = fmaxf(o, 0.f);  // relu (both layers use relu)
}

// ---------------- fused mean pool + linear: one block per graph ----------------
__global__ __launch_bounds__(256) void k_pool_final(const float* __restrict__ h,
    const int* __restrict__ batch, const float* __restrict__ Wlin,
    const float* __restrict__ blin, float* __restrict__ out, int n) {
  int g = blockIdx.x;
  int lo = 0, hi = n;
  while (lo < hi) { int mid = (lo + hi) >> 1; if (batch[mid] < g) lo = mid + 1; else hi = mid; }
  int beg = lo;
  hi = n;
  while (lo < hi) { int mid = (lo + hi) >> 1; if (batch[mid] < g + 1) lo = mid + 1; else hi = mid; }
  int end = lo;

  float w[8];
  #pragma unroll
  for (int c = 0; c < 8; c++) w[c] = Wlin[c];

  float acc = 0.f;
  int t = threadIdx.x;
  for (int i = beg + t; i < end; i += 256) {
    const float4* hp = reinterpret_cast<const float4*>(h + (long)i * 8);
    float4 v0 = hp[0], v1 = hp[1];
    acc += v0.x * w[0] + v0.y * w[1] + v0.z * w[2] + v0.w * w[3]
         + v1.x * w[4] + v1.y * w[5] + v1.z * w[6] + v1.w * w[7];
  }
  #pragma unroll
  for (int off = 32; off; off >>= 1) acc += __shfl_down(acc, off, 64);
  __shared__ float sh[4];
  if ((t & 63) == 0) sh[t >> 6] = acc;
  __syncthreads();
  if (t == 0) {
    float total = sh[0] + sh[1] + sh[2] + sh[3];
    float cnt = (float)(end - beg);
    out[g] = total / fmaxf(cnt, 1.f) + blin[0];
  }
}

extern "C" void kernel_launch(void* const* d_in, const int* in_sizes, int n_in,
                              void* d_out, int out_size, void* d_ws, size_t ws_size,
                              hipStream_t stream) {
  (void)n_in; (void)ws_size;
  const float* x    = (const float*)d_in[0];
  const int*   ei   = (const int*)d_in[1];
  const int*   batch= (const int*)d_in[2];
  const float* W1l  = (const float*)d_in[3];
  const float* W1r  = (const float*)d_in[4];
  const float* a1   = (const float*)d_in[5];
  const float* b1   = (const float*)d_in[6];
  const float* W2l  = (const float*)d_in[7];
  const float* W2r  = (const float*)d_in[8];
  const float* a2   = (const float*)d_in[9];
  const float* b2   = (const float*)d_in[10];
  const float* Wlin = (const float*)d_in[11];
  const float* blin = (const float*)d_in[12];
  float* out = (float*)d_out;

  int N = in_sizes[0] / 128;
  int E = in_sizes[1] / 2;
  int G = out_size;            // 256 graphs
  int ET = E + N;              // edges incl self loops
  int BW = (N + NB - 1) / NB;  // nodes per bucket
  int chunk = (ET + NBLK - 1) / NBLK;
  int nA = NB * NBLK;          // 131072

  char* ws = (char*)d_ws;
  size_t off = 0;
  auto alloc = [&](size_t bytes) {
    void* p = ws + off; off = (off + bytes + 255) & ~(size_t)255; return p;
  };
  int* csr_ptr = (int*)alloc((size_t)(N + 1) * 4);
  int* A       = (int*)alloc((size_t)(nA + 1) * 4);
  int* bsum    = (int*)alloc(512 * 4);
  int* csr_src = (int*)alloc((size_t)ET * 4);
  // union: pairs (ET*8 B) time-shared with feature buffers (N*288 B)
  size_t featBytes = (size_t)N * (16 + 16 + 16 + 8 + 8 + 8) * 4;
  size_t pairBytes = (size_t)ET * 8;
  char* u = (char*)alloc(pairBytes > featBytes ? pairBytes : featBytes);
  int2* pairs = (int2*)u;
  float* xl1 = (float*)u;
  float* xr1 = xl1 + (size_t)N * 16;
  float* h1  = xr1 + (size_t)N * 16;
  float* xl2 = h1  + (size_t)N * 16;
  float* xr2 = xl2 + (size_t)N * 8;
  float* h2  = xr2 + (size_t)N * 8;

  k_bin_count<<<NBLK, 256, 0, stream>>>(ei, E, ET, BW, chunk, A);
  k_reduce<<<(nA + 255) / 256, 256, 0, stream>>>(A, bsum, nA);
  k_scan_bsum<<<1, 512, 0, stream>>>(bsum, (nA + 255) / 256);
  k_scan_apply<<<(nA + 255) / 256, 256, 0, stream>>>(A, bsum, nA);
  k_bin_scatter<<<NBLK, 256, 0, stream>>>(ei, E, ET, BW, chunk, A, pairs);
  k_csr_build<<<NB, 256, 0, stream>>>(pairs, A, csr_ptr, csr_src, BW, N, ET);
  k_gemm1<<<(N + 63) / 64, 256, 0, stream>>>(x, W1l, W1r, xl1, xr1, N);
  k_edge<16, 4><<<(N + 15) / 16, 256, 0, stream>>>(csr_ptr, csr_src, xl1, xr1, a1, b1, h1, N);
  k_gemm2<<<(N + 255) / 256, 256, 0, stream>>>(h1, W2l, W2r, xl2, xr2, N);
  k_edge<8, 4><<<(N + 31) / 32, 256, 0, stream>>>(csr_ptr, csr_src, xl2, xr2, a2, b2, h2, N);
  k_pool_final<<<G, 256, 0, stream>>>(h2, batch, Wlin, blin, out, N);
}